// Round 1
// baseline (295.906 us; speedup 1.0000x reference)
//
#include <hip/hip_runtime.h>

typedef __attribute__((ext_vector_type(8))) short short8;
typedef __attribute__((ext_vector_type(4))) float f32x4;
typedef unsigned short ushort_t;
typedef unsigned int uint_t;

#define SEQ 4096
#define NB 4
#define EMB 1024
#define HD 128

__device__ __forceinline__ ushort_t f2bf(float f) {
  uint_t u = __float_as_uint(f);
  u += 0x7fffu + ((u >> 16) & 1u);
  return (ushort_t)(u >> 16);
}

// -------------------- Kernel 0: weight transpose+convert --------------------
// Wt[o][n][k] = bf16(W_o[k][n]);  o: 0=Wq, 1=Wk, 2=Wv
__global__ __launch_bounds__(256) void wt_prep(const float* __restrict__ Wq,
                                               const float* __restrict__ Wk,
                                               const float* __restrict__ Wv,
                                               ushort_t* __restrict__ Wt) {
  int idx = blockIdx.x * 256 + threadIdx.x;  // exactly 3*131072 threads
  int o = idx >> 17;
  int r = idx & 131071;
  int k = r >> 7;
  int n = r & 127;
  const float* W = (o == 0) ? Wq : ((o == 1) ? Wk : Wv);
  Wt[o * 131072 + n * 1024 + k] = f2bf(W[k * 128 + n]);
}

// -------------------- Kernel 1: QKV projection (bf16 MFMA) --------------------
// grid: 768 blocks; o = bid>>8 (0=q,1=k,2=v), 64 rows per block, 4 waves x 16 rows.
// Outputs: qb/kb [16384][128] bf16 (q pre-scaled by 1/32), vt [4][128][4096] bf16.
__global__ __launch_bounds__(256) void proj(const float* __restrict__ x,
                                            const ushort_t* __restrict__ Wt,
                                            ushort_t* __restrict__ qb,
                                            ushort_t* __restrict__ kb,
                                            ushort_t* __restrict__ vt) {
  __shared__ __align__(16) ushort_t wlds[128][72];  // pad 64->72: 2-way conflicts
  int bid = blockIdx.x;
  int o = bid >> 8;
  int m0 = (bid & 255) * 64;
  int tid = threadIdx.x;
  int w = tid >> 6;
  int l = tid & 63;
  int l15 = l & 15, lg = l >> 4;

  const ushort_t* Wto = Wt + o * 131072;
  f32x4 acc[8];
#pragma unroll
  for (int i = 0; i < 8; ++i) acc[i] = (f32x4){0.f, 0.f, 0.f, 0.f};

  int sn = tid >> 1;            // staging row (n)
  int skh = (tid & 1) * 32;     // staging k-half
  const float* xrow = x + (size_t)(m0 + w * 16 + l15) * 1024;

  for (int kc = 0; kc < 16; ++kc) {
    {  // stage Wt tile [128 n][64 k] into LDS (vectorized 16B)
      const ushort_t* src = Wto + sn * 1024 + kc * 64 + skh;
      uint4* dst = (uint4*)&wlds[sn][skh];
#pragma unroll
      for (int i = 0; i < 4; ++i) dst[i] = ((const uint4*)src)[i];
    }
    __syncthreads();
    // A fragments from x (fp32 -> bf16 in-register)
    short8 a[2];
#pragma unroll
    for (int c = 0; c < 2; ++c) {
      const float* xp = xrow + kc * 64 + c * 32 + lg * 8;
      float4 x0 = *(const float4*)xp;
      float4 x1 = *(const float4*)(xp + 4);
      short8 af;
      af[0] = f2bf(x0.x); af[1] = f2bf(x0.y); af[2] = f2bf(x0.z); af[3] = f2bf(x0.w);
      af[4] = f2bf(x1.x); af[5] = f2bf(x1.y); af[6] = f2bf(x1.z); af[7] = f2bf(x1.w);
      a[c] = af;
    }
#pragma unroll
    for (int fi = 0; fi < 8; ++fi) {
#pragma unroll
      for (int c = 0; c < 2; ++c) {
        short8 bf = *(const short8*)&wlds[fi * 16 + l15][c * 32 + lg * 8];
        acc[fi] = __builtin_amdgcn_mfma_f32_16x16x32_bf16(a[c], bf, acc[fi], 0, 0, 0);
      }
    }
    __syncthreads();
  }

  // epilogue: C layout col = lane&15, row = (lane>>4)*4 + j
  int rbase = m0 + w * 16 + lg * 4;
  if (o == 0) {
#pragma unroll
    for (int fi = 0; fi < 8; ++fi)
#pragma unroll
      for (int j = 0; j < 4; ++j)
        qb[(size_t)(rbase + j) * 128 + fi * 16 + l15] = f2bf(acc[fi][j] * 0.03125f);
  } else if (o == 1) {
#pragma unroll
    for (int fi = 0; fi < 8; ++fi)
#pragma unroll
      for (int j = 0; j < 4; ++j)
        kb[(size_t)(rbase + j) * 128 + fi * 16 + l15] = f2bf(acc[fi][j]);
  } else {
#pragma unroll
    for (int fi = 0; fi < 8; ++fi)
#pragma unroll
      for (int j = 0; j < 4; ++j) {
        int s = rbase + j;
        int bb = s >> 12;
        int sb = s & 4095;
        vt[((size_t)(bb * 128 + fi * 16 + l15)) * 4096 + sb] = f2bf(acc[fi][j]);
      }
  }
}

// -------------------- Kernel 2: causal flash attention --------------------
// grid: 1024 blocks = iq*4 + batch. Block = one 16-row q-tile, 4 waves split-K
// over 64-key kv tiles (wave w: tiles w, w+4, ...), LDS merge at the end.
__global__ __launch_bounds__(256) void attn(const ushort_t* __restrict__ qb,
                                            const ushort_t* __restrict__ kb,
                                            const ushort_t* __restrict__ vt,
                                            float* __restrict__ out) {
  __shared__ __align__(16) float smem[8320];  // 33280 B: p_lds aliases acc area
  int bid = blockIdx.x;
  int b = bid & 3;
  int iq = bid >> 2;
  int q0 = iq * 16;
  int tid = threadIdx.x;
  int w = tid >> 6;
  int l = tid & 63;
  int l15 = l & 15, lg = l >> 4;

  ushort_t* p_base = (ushort_t*)smem + w * 1152;  // per-wave [16][72] bf16

  // Q fragments (q pre-scaled by 1/sqrt(1024) in proj)
  const ushort_t* qp = qb + (size_t)(b * 4096 + q0 + l15) * 128;
  short8 aq[4];
#pragma unroll
  for (int c = 0; c < 4; ++c) aq[c] = *(const short8*)(qp + c * 32 + lg * 8);

  f32x4 accO[8];
#pragma unroll
  for (int i = 0; i < 8; ++i) accO[i] = (f32x4){0.f, 0.f, 0.f, 0.f};
  float m[4] = {-__builtin_inff(), -__builtin_inff(), -__builtin_inff(), -__builtin_inff()};
  float lsum[4] = {0.f, 0.f, 0.f, 0.f};

  int nt = (q0 + 15) / 64 + 1;  // causal tile count (kb0_last <= q0 always)
  for (int t = w; t < nt; t += 4) {
    int kb0 = t * 64;
    const ushort_t* kp = kb + (size_t)(b * 4096 + kb0) * 128;
    f32x4 s[4];
#pragma unroll
    for (int i = 0; i < 4; ++i) s[i] = (f32x4){0.f, 0.f, 0.f, 0.f};
#pragma unroll
    for (int fi = 0; fi < 4; ++fi) {
      const ushort_t* kpf = kp + (size_t)(fi * 16 + l15) * 128 + lg * 8;
#pragma unroll
      for (int c = 0; c < 4; ++c) {
        short8 bk = *(const short8*)(kpf + c * 32);
        s[fi] = __builtin_amdgcn_mfma_f32_16x16x32_bf16(aq[c], bk, s[fi], 0, 0, 0);
      }
    }
    if (kb0 + 63 > q0) {  // only the diagonal tile needs masking
#pragma unroll
      for (int fi = 0; fi < 4; ++fi) {
        int key = kb0 + fi * 16 + l15;
#pragma unroll
        for (int j = 0; j < 4; ++j)
          if (key > q0 + lg * 4 + j) s[fi][j] = -__builtin_inff();
      }
    }
    // online softmax: row = (lane>>4)*4 + j, 16 cols live in 16-lane group
    float tm[4], rs[4];
#pragma unroll
    for (int j = 0; j < 4; ++j)
      tm[j] = fmaxf(fmaxf(s[0][j], s[1][j]), fmaxf(s[2][j], s[3][j]));
#pragma unroll
    for (int d = 1; d < 16; d <<= 1)
#pragma unroll
      for (int j = 0; j < 4; ++j) tm[j] = fmaxf(tm[j], __shfl_xor(tm[j], d));
    float mnew[4], sc[4];
#pragma unroll
    for (int j = 0; j < 4; ++j) {
      mnew[j] = fmaxf(m[j], tm[j]);
      sc[j] = __expf(m[j] - mnew[j]);
      rs[j] = 0.f;
    }
#pragma unroll
    for (int fi = 0; fi < 4; ++fi)
#pragma unroll
      for (int j = 0; j < 4; ++j) {
        float p = __expf(s[fi][j] - mnew[j]);
        s[fi][j] = p;
        rs[j] += p;
      }
#pragma unroll
    for (int d = 1; d < 16; d <<= 1)
#pragma unroll
      for (int j = 0; j < 4; ++j) rs[j] += __shfl_xor(rs[j], d);
#pragma unroll
    for (int j = 0; j < 4; ++j) {
      lsum[j] = lsum[j] * sc[j] + rs[j];
      m[j] = mnew[j];
    }
#pragma unroll
    for (int f = 0; f < 8; ++f)
#pragma unroll
      for (int j = 0; j < 4; ++j) accO[f][j] *= sc[j];
    // P (C layout) -> LDS -> A fragments
#pragma unroll
    for (int fi = 0; fi < 4; ++fi)
#pragma unroll
      for (int j = 0; j < 4; ++j)
        p_base[(lg * 4 + j) * 72 + fi * 16 + l15] = f2bf(s[fi][j]);
    short8 ap0 = *(const short8*)&p_base[l15 * 72 + lg * 8];
    short8 ap1 = *(const short8*)&p_base[l15 * 72 + 32 + lg * 8];
    // PV: V^T layout makes B fragments 16B-contiguous
    const ushort_t* vp = vt + (size_t)b * 524288 + kb0 + lg * 8;
#pragma unroll
    for (int f = 0; f < 8; ++f) {
      const ushort_t* vpf = vp + (size_t)(f * 16 + l15) * 4096;
      short8 bv0 = *(const short8*)(vpf);
      short8 bv1 = *(const short8*)(vpf + 32);
      accO[f] = __builtin_amdgcn_mfma_f32_16x16x32_bf16(ap0, bv0, accO[f], 0, 0, 0);
      accO[f] = __builtin_amdgcn_mfma_f32_16x16x32_bf16(ap1, bv1, accO[f], 0, 0, 0);
    }
  }

  __syncthreads();  // protects p_lds alias before merge-area writes
  float* acc_area = smem;          // [64][128]: (w*16+row) x col
  float* ml_area = smem + 8192;    // [64][2]
#pragma unroll
  for (int f = 0; f < 8; ++f)
#pragma unroll
    for (int j = 0; j < 4; ++j)
      acc_area[(w * 16 + lg * 4 + j) * 128 + f * 16 + l15] = accO[f][j];
  if (l15 == 0) {
#pragma unroll
    for (int j = 0; j < 4; ++j) {
      ml_area[(w * 16 + lg * 4 + j) * 2 + 0] = m[j];
      ml_area[(w * 16 + lg * 4 + j) * 2 + 1] = lsum[j];
    }
  }
  __syncthreads();

  // merge 4 split-K partials; thread t -> (row = t>>4, cols cg*8..cg*8+7)
  int row = tid >> 4, cg = tid & 15;
  float mw[4], lw[4];
  float M = -__builtin_inff();
#pragma unroll
  for (int wv = 0; wv < 4; ++wv) {
    mw[wv] = ml_area[(wv * 16 + row) * 2 + 0];
    lw[wv] = ml_area[(wv * 16 + row) * 2 + 1];
    M = fmaxf(M, mw[wv]);
  }
  float L = 0.f, coef[4];
#pragma unroll
  for (int wv = 0; wv < 4; ++wv) {
    coef[wv] = __expf(mw[wv] - M);
    L += lw[wv] * coef[wv];
  }
  float inv = 1.0f / L;
  float o8[8];
#pragma unroll
  for (int e = 0; e < 8; ++e) o8[e] = 0.f;
#pragma unroll
  for (int wv = 0; wv < 4; ++wv) {
    const float* ap = &acc_area[(wv * 16 + row) * 128 + cg * 8];
#pragma unroll
    for (int e = 0; e < 8; ++e) o8[e] += ap[e] * coef[wv];
  }
  float4 o0 = {o8[0] * inv, o8[1] * inv, o8[2] * inv, o8[3] * inv};
  float4 o1 = {o8[4] * inv, o8[5] * inv, o8[6] * inv, o8[7] * inv};
  float* op = out + (size_t)(b * 4096 + q0 + row) * 128 + cg * 8;
  *(float4*)op = o0;
  *(float4*)(op + 4) = o1;
}

// -------------------- launch --------------------
extern "C" void kernel_launch(void* const* d_in, const int* in_sizes, int n_in,
                              void* d_out, int out_size, void* d_ws, size_t ws_size,
                              hipStream_t stream) {
  const float* x = (const float*)d_in[0];
  const float* Wk = (const float*)d_in[1];
  const float* Wq = (const float*)d_in[2];
  const float* Wv = (const float*)d_in[3];
  float* out = (float*)d_out;
  char* ws = (char*)d_ws;
  ushort_t* Wt = (ushort_t*)(ws);                        // 786432 B
  ushort_t* qb = (ushort_t*)(ws + 786432);               // 4 MB
  ushort_t* kbp = (ushort_t*)(ws + 786432 + 4194304);    // 4 MB
  ushort_t* vt = (ushort_t*)(ws + 786432 + 8388608);     // 4 MB

  hipLaunchKernelGGL(wt_prep, dim3(1536), dim3(256), 0, stream, Wq, Wk, Wv, Wt);
  hipLaunchKernelGGL(proj, dim3(768), dim3(256), 0, stream, x, Wt, qb, kbp, vt);
  hipLaunchKernelGGL(attn, dim3(1024), dim3(256), 0, stream, qb, kbp, vt, out);
}

// Round 2
// 252.298 us; speedup vs baseline: 1.1728x; 1.1728x over previous
//
#include <hip/hip_runtime.h>

typedef __attribute__((ext_vector_type(8))) short short8;
typedef __attribute__((ext_vector_type(4))) float f32x4;
typedef unsigned short ushort_t;
typedef unsigned int uint_t;

#define SEQ 4096
#define NB 4
#define EMB 1024
#define HD 128

__device__ __forceinline__ ushort_t f2bf(float f) {
  uint_t u = __float_as_uint(f);
  u += 0x7fffu + ((u >> 16) & 1u);
  return (ushort_t)(u >> 16);
}
__device__ __forceinline__ float bf2f(ushort_t h) {
  return __uint_as_float(((uint_t)h) << 16);
}

// -------------------- Kernel 0: weight transpose+convert --------------------
// Wt[o][n][k] = bf16(W_o[k][n]);  o: 0=Wq, 1=Wk, 2=Wv
__global__ __launch_bounds__(256) void wt_prep(const float* __restrict__ Wq,
                                               const float* __restrict__ Wk,
                                               const float* __restrict__ Wv,
                                               ushort_t* __restrict__ Wt) {
  int idx = blockIdx.x * 256 + threadIdx.x;  // 3*131072 threads
  int o = idx >> 17;
  int r = idx & 131071;
  int k = r >> 7;
  int n = r & 127;
  const float* W = (o == 0) ? Wq : ((o == 1) ? Wk : Wv);
  Wt[o * 131072 + n * 1024 + k] = f2bf(W[k * 128 + n]);
}

// -------------------- Kernel 1: fused QKV projection --------------------
// 256 blocks x 256 thr; block = 64 rows of x, computes q,k,v in ONE pass over x.
// W tiles (3 x [128][64] bf16) staged in LDS with granule-XOR swizzle.
__global__ __launch_bounds__(256, 2) void proj(const float* __restrict__ x,
                                               const ushort_t* __restrict__ Wt,
                                               ushort_t* __restrict__ qb,
                                               ushort_t* __restrict__ kb,
                                               ushort_t* __restrict__ vt) {
  __shared__ __align__(16) ushort_t wlds[3][128][64];  // 48 KB
  int m0 = blockIdx.x * 64;
  int tid = threadIdx.x;
  int w = tid >> 6, l = tid & 63, l15 = l & 15, lg = l >> 4;

  f32x4 acc[3][8];
#pragma unroll
  for (int o = 0; o < 3; ++o)
#pragma unroll
    for (int i = 0; i < 8; ++i) acc[o][i] = (f32x4){0.f, 0.f, 0.f, 0.f};

  const float* xrow = x + (size_t)(m0 + w * 16 + l15) * 1024;

  for (int kc = 0; kc < 16; ++kc) {
    // stage 3 W tiles: 3072 granules of 16B, swizzled dest
#pragma unroll
    for (int i = 0; i < 12; ++i) {
      int G = i * 256 + tid;
      int o = G >> 10, r = (G >> 3) & 127, g = G & 7;
      uint4 v = *(const uint4*)(Wt + o * 131072 + r * 1024 + kc * 64 + g * 8);
      *(uint4*)&wlds[o][r][(g ^ (r & 7)) * 8] = v;
    }
    __syncthreads();
    // A fragments from x (fp32 -> bf16 in-register)
    short8 a[2];
#pragma unroll
    for (int c = 0; c < 2; ++c) {
      const float* xp = xrow + kc * 64 + c * 32 + lg * 8;
      float4 x0 = *(const float4*)xp;
      float4 x1 = *(const float4*)(xp + 4);
      short8 af;
      af[0] = f2bf(x0.x); af[1] = f2bf(x0.y); af[2] = f2bf(x0.z); af[3] = f2bf(x0.w);
      af[4] = f2bf(x1.x); af[5] = f2bf(x1.y); af[6] = f2bf(x1.z); af[7] = f2bf(x1.w);
      a[c] = af;
    }
#pragma unroll
    for (int o = 0; o < 3; ++o)
#pragma unroll
      for (int fi = 0; fi < 8; ++fi)
#pragma unroll
        for (int c = 0; c < 2; ++c) {
          short8 bf = *(const short8*)&wlds[o][fi * 16 + l15][((c * 4 + lg) ^ (l15 & 7)) * 8];
          acc[o][fi] = __builtin_amdgcn_mfma_f32_16x16x32_bf16(a[c], bf, acc[o][fi], 0, 0, 0);
        }
    __syncthreads();
  }

  int rbase = m0 + w * 16 + lg * 4;
#pragma unroll
  for (int fi = 0; fi < 8; ++fi)
#pragma unroll
    for (int j = 0; j < 4; ++j) {
      qb[(size_t)(rbase + j) * 128 + fi * 16 + l15] = f2bf(acc[0][fi][j] * 0.03125f);
      kb[(size_t)(rbase + j) * 128 + fi * 16 + l15] = f2bf(acc[1][fi][j]);
      int s = rbase + j;
      vt[((size_t)((s >> 12) * 128 + fi * 16 + l15)) * 4096 + (s & 4095)] = f2bf(acc[2][fi][j]);
    }
}

// -------------------- Kernel 2: sliced causal flash attention --------------------
// Strips of 128 q-rows (4 waves x 32 rows). kv units of 64 keys; strip s has
// nt=2s+2 units, split into ns=(s/4)+1 slices (<=8 units each) -> 144 entries/batch,
// 576 blocks total. K/V staged once per block-unit into XOR-swizzled LDS.
// Partials: bf16 O + f32 (m,l) per row, merged by attn_merge.
__global__ __launch_bounds__(256, 2) void attn_slice(const ushort_t* __restrict__ qb,
                                                     const ushort_t* __restrict__ kb,
                                                     const ushort_t* __restrict__ vt,
                                                     ushort_t* __restrict__ pO,
                                                     float* __restrict__ pML) {
  __shared__ __align__(16) ushort_t ldsK[64][128];   // 16 KB, granule g^=r&15
  __shared__ __align__(16) ushort_t ldsV[128][64];   // 16 KB, granule g^=r&7 (V^T)
  __shared__ __align__(16) ushort_t ldsP[4][32][64]; // 16 KB, per-wave P, g^=row&7

  int bid = blockIdx.x;
  int e = 143 - (bid >> 2);  // reversed: heavy entries first
  int b = bid & 3;
  // decode e -> (strip s, slice j): group g=s/4 has 4 strips x (g+1) slices
  int s = 0, j = 0, base = 0;
#pragma unroll
  for (int g = 0; g < 8; ++g) {
    int sz = 4 * (g + 1);
    if (e < base + sz) {
      int r = e - base;
      s = 4 * g + r / (g + 1);
      j = r % (g + 1);
      break;
    }
    base += sz;
  }
  int nt = 2 * s + 2, ns = (s >> 2) + 1;
  int u0 = j * nt / ns, u1 = (j + 1) * nt / ns;

  int tid = threadIdx.x, w = tid >> 6, l = tid & 63, l15 = l & 15, lg = l >> 4;
  int r0w = 128 * s + 32 * w;  // wave's min q-row (batch-local)

  const ushort_t* qp = qb + (size_t)(b * 4096 + r0w + l15) * 128;
  short8 aq[2][4];
#pragma unroll
  for (int h = 0; h < 2; ++h)
#pragma unroll
    for (int c = 0; c < 4; ++c) aq[h][c] = *(const short8*)(qp + h * 2048 + c * 32 + lg * 8);

  f32x4 accO[2][8];
#pragma unroll
  for (int h = 0; h < 2; ++h)
#pragma unroll
    for (int i = 0; i < 8; ++i) accO[h][i] = (f32x4){0.f, 0.f, 0.f, 0.f};
  float m[2][4], lsum[2][4];
#pragma unroll
  for (int h = 0; h < 2; ++h)
#pragma unroll
    for (int jj = 0; jj < 4; ++jj) { m[h][jj] = -1e30f; lsum[h][jj] = 0.f; }

  for (int u = u0; u < u1; ++u) {
    {  // stage K tile [64 keys][128] (1024 granules) + V^T tile [128 d][64] (1024)
      const ushort_t* ksrc = kb + ((size_t)b * 4096 + u * 64) * 128;
#pragma unroll
      for (int i = 0; i < 4; ++i) {
        int d = i * 256 + tid;
        int r = d >> 4, g = d & 15;
        uint4 v = *(const uint4*)(ksrc + r * 128 + g * 8);
        *(uint4*)&ldsK[r][(g ^ (r & 15)) * 8] = v;
      }
      const ushort_t* vsrc = vt + (size_t)b * 524288 + u * 64;
#pragma unroll
      for (int i = 0; i < 4; ++i) {
        int d = i * 256 + tid;
        int r = d >> 3, g = d & 7;
        uint4 v = *(const uint4*)(vsrc + (size_t)r * 4096 + g * 8);
        *(uint4*)&ldsV[r][(g ^ (r & 7)) * 8] = v;
      }
    }
    __syncthreads();
    bool skip = (64 * u > r0w + 31);
    if (!skip) {
      f32x4 s_[2][4];
#pragma unroll
      for (int h = 0; h < 2; ++h)
#pragma unroll
        for (int fi = 0; fi < 4; ++fi) s_[h][fi] = (f32x4){0.f, 0.f, 0.f, 0.f};
#pragma unroll
      for (int c = 0; c < 4; ++c)
#pragma unroll
        for (int fi = 0; fi < 4; ++fi) {
          short8 bk = *(const short8*)&ldsK[fi * 16 + l15][((c * 4 + lg) ^ l15) * 8];
          s_[0][fi] = __builtin_amdgcn_mfma_f32_16x16x32_bf16(aq[0][c], bk, s_[0][fi], 0, 0, 0);
          s_[1][fi] = __builtin_amdgcn_mfma_f32_16x16x32_bf16(aq[1][c], bk, s_[1][fi], 0, 0, 0);
        }
      if (64 * u + 63 > r0w) {  // diagonal-straddling unit: causal mask
#pragma unroll
        for (int h = 0; h < 2; ++h)
#pragma unroll
          for (int fi = 0; fi < 4; ++fi) {
            int key = 64 * u + fi * 16 + l15;
#pragma unroll
            for (int jj = 0; jj < 4; ++jj)
              if (key > r0w + h * 16 + lg * 4 + jj) s_[h][fi][jj] = -__builtin_inff();
          }
      }
      // online softmax (rows in lg-groups; keys across l15 lanes + fi regs)
      float tm[2][4];
#pragma unroll
      for (int h = 0; h < 2; ++h)
#pragma unroll
        for (int jj = 0; jj < 4; ++jj)
          tm[h][jj] = fmaxf(fmaxf(s_[h][0][jj], s_[h][1][jj]), fmaxf(s_[h][2][jj], s_[h][3][jj]));
#pragma unroll
      for (int d = 1; d < 16; d <<= 1)
#pragma unroll
        for (int h = 0; h < 2; ++h)
#pragma unroll
          for (int jj = 0; jj < 4; ++jj) tm[h][jj] = fmaxf(tm[h][jj], __shfl_xor(tm[h][jj], d));
      float sc[2][4], rs[2][4], mn[2][4];
#pragma unroll
      for (int h = 0; h < 2; ++h)
#pragma unroll
        for (int jj = 0; jj < 4; ++jj) {
          mn[h][jj] = fmaxf(m[h][jj], tm[h][jj]);
          sc[h][jj] = __expf(m[h][jj] - mn[h][jj]);
          rs[h][jj] = 0.f;
        }
#pragma unroll
      for (int h = 0; h < 2; ++h)
#pragma unroll
        for (int fi = 0; fi < 4; ++fi)
#pragma unroll
          for (int jj = 0; jj < 4; ++jj) {
            float p = __expf(s_[h][fi][jj] - mn[h][jj]);
            s_[h][fi][jj] = p;
            rs[h][jj] += p;
          }
#pragma unroll
      for (int d = 1; d < 16; d <<= 1)
#pragma unroll
        for (int h = 0; h < 2; ++h)
#pragma unroll
          for (int jj = 0; jj < 4; ++jj) rs[h][jj] += __shfl_xor(rs[h][jj], d);
#pragma unroll
      for (int h = 0; h < 2; ++h)
#pragma unroll
        for (int jj = 0; jj < 4; ++jj) {
          lsum[h][jj] = lsum[h][jj] * sc[h][jj] + rs[h][jj];
          m[h][jj] = mn[h][jj];
        }
#pragma unroll
      for (int h = 0; h < 2; ++h)
#pragma unroll
        for (int f = 0; f < 8; ++f)
#pragma unroll
          for (int jj = 0; jj < 4; ++jj) accO[h][f][jj] *= sc[h][jj];
      // P -> LDS (swizzled) -> A frags
#pragma unroll
      for (int h = 0; h < 2; ++h)
#pragma unroll
        for (int fi = 0; fi < 4; ++fi)
#pragma unroll
          for (int jj = 0; jj < 4; ++jj) {
            int row = h * 16 + lg * 4 + jj;
            int gidx = fi * 2 + (l15 >> 3);
            ldsP[w][row][((gidx ^ (row & 7)) << 3) | (l15 & 7)] = f2bf(s_[h][fi][jj]);
          }
      short8 ap[2][2];
#pragma unroll
      for (int h = 0; h < 2; ++h)
#pragma unroll
        for (int c = 0; c < 2; ++c)
          ap[h][c] = *(const short8*)&ldsP[w][h * 16 + l15][((c * 4 + lg) ^ (l15 & 7)) * 8];
#pragma unroll
      for (int c = 0; c < 2; ++c)
#pragma unroll
        for (int f = 0; f < 8; ++f) {
          short8 bv = *(const short8*)&ldsV[f * 16 + l15][((c * 4 + lg) ^ (l15 & 7)) * 8];
          accO[0][f] = __builtin_amdgcn_mfma_f32_16x16x32_bf16(ap[0][c], bv, accO[0][f], 0, 0, 0);
          accO[1][f] = __builtin_amdgcn_mfma_f32_16x16x32_bf16(ap[1][c], bv, accO[1][f], 0, 0, 0);
        }
    }
    __syncthreads();
  }

  // write partials
  size_t obase = (size_t)bid * 16384;
#pragma unroll
  for (int h = 0; h < 2; ++h)
#pragma unroll
    for (int f = 0; f < 8; ++f)
#pragma unroll
      for (int jj = 0; jj < 4; ++jj) {
        int row = w * 32 + h * 16 + lg * 4 + jj;
        pO[obase + (size_t)row * 128 + f * 16 + l15] = f2bf(accO[h][f][jj]);
      }
  if (l15 == 0) {
#pragma unroll
    for (int h = 0; h < 2; ++h)
#pragma unroll
      for (int jj = 0; jj < 4; ++jj) {
        int row = w * 32 + h * 16 + lg * 4 + jj;
        pML[(size_t)bid * 256 + row * 2 + 0] = m[h][jj];
        pML[(size_t)bid * 256 + row * 2 + 1] = lsum[h][jj];
      }
  }
}

// -------------------- Kernel 3: merge split-K partials --------------------
__global__ __launch_bounds__(256) void attn_merge(const ushort_t* __restrict__ pO,
                                                  const float* __restrict__ pML,
                                                  float* __restrict__ out) {
  int idx = blockIdx.x * 256 + threadIdx.x;  // 524288 threads
  int row = idx >> 5;                        // [0,16384)
  int cg = (idx & 31) * 4;
  int b = row >> 12, sr = row & 4095;
  int s = sr >> 7, g = s >> 2, ns = g + 1;
  int cumS = (g + 1) * (s - 2 * g);
  int rr = sr & 127;
  int e0 = 143 - (cumS + ns - 1);  // entries were reversed in attn_slice
  // block id for slice j: e = cumS + j -> bid = (143 - e)*4 + b
  float M = -1e30f;
  for (int j = 0; j < ns; ++j) {
    int gid = (143 - (cumS + j)) * 4 + b;
    M = fmaxf(M, pML[(size_t)gid * 256 + rr * 2 + 0]);
  }
  float L = 0.f;
  float o0 = 0.f, o1 = 0.f, o2 = 0.f, o3 = 0.f;
  for (int j = 0; j < ns; ++j) {
    int gid = (143 - (cumS + j)) * 4 + b;
    float mv = pML[(size_t)gid * 256 + rr * 2 + 0];
    float lv = pML[(size_t)gid * 256 + rr * 2 + 1];
    float coef = __expf(mv - M);
    L += lv * coef;
    const ushort_t* op = pO + (size_t)gid * 16384 + rr * 128 + cg;
    uint2 pv = *(const uint2*)op;
    o0 += coef * bf2f((ushort_t)(pv.x & 0xffff));
    o1 += coef * bf2f((ushort_t)(pv.x >> 16));
    o2 += coef * bf2f((ushort_t)(pv.y & 0xffff));
    o3 += coef * bf2f((ushort_t)(pv.y >> 16));
  }
  (void)e0;
  float inv = 1.0f / L;
  float4 r = {o0 * inv, o1 * inv, o2 * inv, o3 * inv};
  *(float4*)(out + (size_t)row * 128 + cg) = r;
}

// -------------------- launch --------------------
extern "C" void kernel_launch(void* const* d_in, const int* in_sizes, int n_in,
                              void* d_out, int out_size, void* d_ws, size_t ws_size,
                              hipStream_t stream) {
  const float* x = (const float*)d_in[0];
  const float* Wk = (const float*)d_in[1];
  const float* Wq = (const float*)d_in[2];
  const float* Wv = (const float*)d_in[3];
  float* out = (float*)d_out;
  char* ws = (char*)d_ws;
  ushort_t* Wt = (ushort_t*)(ws);                         // 768 KB
  ushort_t* qb = (ushort_t*)(ws + 786432);                // 4 MB
  ushort_t* kbp = (ushort_t*)(ws + 786432 + 4194304);     // 4 MB
  ushort_t* vt = (ushort_t*)(ws + 786432 + 8388608);      // 4 MB
  ushort_t* pO = (ushort_t*)(ws + 13369344);              // 18.87 MB (576*16384 bf16)
  float* pML = (float*)(ws + 32243712);                   // 0.59 MB (576*128*2 f32)

  hipLaunchKernelGGL(wt_prep, dim3(1536), dim3(256), 0, stream, Wq, Wk, Wv, Wt);
  hipLaunchKernelGGL(proj, dim3(256), dim3(256), 0, stream, x, Wt, qb, kbp, vt);
  hipLaunchKernelGGL(attn_slice, dim3(576), dim3(256), 0, stream, qb, kbp, vt, pO, pML);
  hipLaunchKernelGGL(attn_merge, dim3(2048), dim3(256), 0, stream, pO, pML, out);
}